// Round 1
// baseline (181.165 us; speedup 1.0000x reference)
//
#include <hip/hip_runtime.h>
#include <math.h>

#define SEQ 512
#define FDIM 64
#define D 8

__global__ __launch_bounds__(512, 1) void hybrid_attn_kernel(
    const float* __restrict__ state,    // [B,S,F]
    const float* __restrict__ proj_w,   // [F,D]
    const float* __restrict__ proj_b,   // [D]
    const float* __restrict__ rotation, // [D,D]
    const float* __restrict__ entangle, // [D,D]
    const float* __restrict__ w1,       // [D,32]
    const float* __restrict__ b1,       // [32]
    const float* __restrict__ w2,       // [32,16]
    const float* __restrict__ b2,       // [16]
    const float* __restrict__ w3,       // [16,1]
    const float* __restrict__ b3,       // [1]
    float* __restrict__ out)            // [B,S]
{
    __shared__ __align__(16) float s_proj[SEQ][D];   // 16 KB  (the V matrix too)
    __shared__ __align__(16) float s_k[SEQ][D];      // 16 KB
    __shared__ float s_pw[FDIM][D];                  // 2 KB
    __shared__ float s_rot[D][D];
    __shared__ float s_ent[D][D];
    __shared__ float s_pb[D];
    __shared__ float s_w1[D * 32];
    __shared__ float s_b1[32];
    __shared__ float s_w2[32 * 16];
    __shared__ float s_b2[16];
    __shared__ float s_w3[16];
    __shared__ float s_b3[1];

    const int b   = blockIdx.x;
    const int tid = threadIdx.x;

    // ---- stage small weights into LDS ----
    if (tid < FDIM * D) s_pw[tid >> 3][tid & 7] = proj_w[tid];
    if (tid < D * D) {
        s_rot[tid >> 3][tid & 7] = rotation[tid];
        s_ent[tid >> 3][tid & 7] = entangle[tid];
    }
    if (tid < D)       s_pb[tid] = proj_b[tid];
    if (tid < D * 32)  s_w1[tid] = w1[tid];
    if (tid < 32)      s_b1[tid] = b1[tid];
    if (tid < 32 * 16) s_w2[tid] = w2[tid];
    if (tid < 16)      s_b2[tid] = b2[tid];
    if (tid < 16)      s_w3[tid] = w3[tid];
    if (tid == 0)      s_b3[0]   = b3[0];
    __syncthreads();

    // ---- phase 1: proj = state @ proj_w + proj_b ; q,k = proj @ rot/ent ----
    const int srow = tid;  // one thread per sequence row, 512 threads = SEQ
    float pj[D];
    #pragma unroll
    for (int j = 0; j < D; j++) pj[j] = s_pb[j];

    const float4* srp = (const float4*)(state + ((size_t)b * SEQ + srow) * FDIM);
    #pragma unroll
    for (int c = 0; c < FDIM / 4; c++) {
        float4 v = srp[c];
        float vs[4] = {v.x, v.y, v.z, v.w};
        #pragma unroll
        for (int u = 0; u < 4; u++) {
            #pragma unroll
            for (int j = 0; j < D; j++) pj[j] += vs[u] * s_pw[c * 4 + u][j];
        }
    }

    float q[D];
    {
        float kk[D];
        #pragma unroll
        for (int j = 0; j < D; j++) {
            float aq = 0.f, ak = 0.f;
            #pragma unroll
            for (int i = 0; i < D; i++) {
                aq += pj[i] * s_rot[i][j];
                ak += pj[i] * s_ent[i][j];
            }
            q[j] = aq; kk[j] = ak;
        }
        #pragma unroll
        for (int j = 0; j < D; j++) { s_proj[srow][j] = pj[j]; s_k[srow][j] = kk[j]; }
    }
    __syncthreads();

    // ---- phase 2: softmax(q k^T / sqrt(d)) @ proj, two-pass ----
    const float scale = 0.35355339059327373f;  // 1/sqrt(8)
    float m = -1e30f;
    #pragma unroll 4
    for (int t = 0; t < SEQ; t++) {
        const float4* kt = (const float4*)s_k[t];   // wave-uniform -> LDS broadcast
        float4 k0 = kt[0], k1 = kt[1];
        float sc = q[0]*k0.x + q[1]*k0.y + q[2]*k0.z + q[3]*k0.w
                 + q[4]*k1.x + q[5]*k1.y + q[6]*k1.z + q[7]*k1.w;
        m = fmaxf(m, sc * scale);
    }

    float l = 0.f;
    float acc[D] = {0.f,0.f,0.f,0.f,0.f,0.f,0.f,0.f};
    #pragma unroll 4
    for (int t = 0; t < SEQ; t++) {
        const float4* kt = (const float4*)s_k[t];
        float4 k0 = kt[0], k1 = kt[1];
        float sc = q[0]*k0.x + q[1]*k0.y + q[2]*k0.z + q[3]*k0.w
                 + q[4]*k1.x + q[5]*k1.y + q[6]*k1.z + q[7]*k1.w;
        float p = __expf(sc * scale - m);
        l += p;
        const float4* pt = (const float4*)s_proj[t];
        float4 p0 = pt[0], p1 = pt[1];
        acc[0] += p * p0.x; acc[1] += p * p0.y; acc[2] += p * p0.z; acc[3] += p * p0.w;
        acc[4] += p * p1.x; acc[5] += p * p1.y; acc[6] += p * p1.z; acc[7] += p * p1.w;
    }
    const float inv_l = 1.0f / l;
    float attn[D];
    #pragma unroll
    for (int j = 0; j < D; j++) attn[j] = acc[j] * inv_l;

    // ---- phase 3: MLP head d -> 32 -> 16 -> 1 ----
    float h1[32];
    #pragma unroll
    for (int j = 0; j < 32; j++) {
        float a = s_b1[j];
        #pragma unroll
        for (int i = 0; i < D; i++) a += attn[i] * s_w1[i * 32 + j];
        h1[j] = fmaxf(a, 0.f);
    }
    float h2[16];
    #pragma unroll
    for (int j = 0; j < 16; j++) {
        float a = s_b2[j];
        #pragma unroll
        for (int i = 0; i < 32; i++) a += h1[i] * s_w2[i * 16 + j];
        h2[j] = fmaxf(a, 0.f);
    }
    float o = s_b3[0];
    #pragma unroll
    for (int i = 0; i < 16; i++) o += h2[i] * s_w3[i];

    out[(size_t)b * SEQ + srow] = o;
}

extern "C" void kernel_launch(void* const* d_in, const int* in_sizes, int n_in,
                              void* d_out, int out_size, void* d_ws, size_t ws_size,
                              hipStream_t stream) {
    const float* state    = (const float*)d_in[0];
    const float* proj_w   = (const float*)d_in[1];
    const float* proj_b   = (const float*)d_in[2];
    const float* rotation = (const float*)d_in[3];
    const float* entangle = (const float*)d_in[4];
    const float* w1       = (const float*)d_in[5];
    const float* b1       = (const float*)d_in[6];
    const float* w2       = (const float*)d_in[7];
    const float* b2       = (const float*)d_in[8];
    const float* w3       = (const float*)d_in[9];
    const float* b3       = (const float*)d_in[10];
    float* out = (float*)d_out;

    const int B = in_sizes[0] / (SEQ * FDIM);  // 256
    hybrid_attn_kernel<<<B, SEQ, 0, stream>>>(
        state, proj_w, proj_b, rotation, entangle,
        w1, b1, w2, b2, w3, b3, out);
}